// Round 3
// baseline (87.083 us; speedup 1.0000x reference)
//
#include <hip/hip_runtime.h>

#define ALPHA 0.2f

constexpr int WDIM = 128;
constexpr int KDIM = 1024;
constexpr int NSEG = 32;             // rank segments for vtab
constexpr int SEGLEN = KDIM / NSEG;  // 32

// per-batch workspace layout (float offsets)
constexpr int OFF_XT   = 0;        // [1024][128]  v = x^T
constexpr int OFF_TAB  = 131072;   // [1025][256]  interleaved: A(c) at [c][w], B(c) at [c][128+w]
constexpr int OFF_ESC  = 393472;   // [1024] exp(s2 - M2) sorted desc
constexpr int OFF_ESCA = 394496;   // [1024] exp(alpha*s2) sorted
constexpr int OFF_ABT  = 395520;   // [1025][2] scalar (a(c), b(c)) interleaved
constexpr int OFF_U    = 397570;   // [1024]
constexpr int OFF_T    = 398594;   // [1024]
constexpr int OFF_S1   = 399618;   // [1024]
constexpr int OFF_S2   = 400642;   // [1024]
constexpr int OFF_CC   = 401666;   // [1024] int: c_i
constexpr int OFF_PERM = 402690;   // [1024] int: perm[rank] = j
constexpr int OFF_TA   = 403840;   // [NSEG][128] segment totals (A side)
constexpr int OFF_TB   = 407936;   // [NSEG][128] segment totals (B side)
constexpr int OFF_STA  = 412032;   // [NSEG] scalar segment totals (a)
constexpr int OFF_STB  = 412064;   // [NSEG] scalar segment totals (b)
constexpr int PBF      = 412160;   // per-batch stride (floats)

// K1: s1, s2, and transpose x -> xT. grid (16, nb) x 256
// block = 64 j's x 4 w-groups of 32; LDS-reduce partial s1/s2 across w-groups.
__global__ __launch_bounds__(256) void k_s12(const float* __restrict__ x,
                                             const float* __restrict__ w,
                                             float* __restrict__ ws, int b0) {
  const int slot = blockIdx.y;
  const int b = b0 + slot;
  float* base = ws + (size_t)slot * PBF;
  __shared__ float w1s[WDIM], w2s[WDIM];
  __shared__ float red1[4][64], red2[4][64];
  int t = threadIdx.x;
  if (t < WDIM) { w1s[t] = w[t]; w2s[t] = w[WDIM + t]; }
  __syncthreads();
  int jj = t & 63, wg = t >> 6;
  int j = blockIdx.x * 64 + jj;
  int w0 = wg * 32;
  const float* xb = x + (size_t)b * (WDIM * KDIM);
  float s1 = 0.f, s2 = 0.f;
  float vals[32];
#pragma unroll
  for (int k = 0; k < 32; ++k) {
    float v = xb[(w0 + k) * KDIM + j];
    vals[k] = v;
    s1 = fmaf(v, w1s[w0 + k], s1);
    s2 = fmaf(v, w2s[w0 + k], s2);
  }
  float* xrow = base + OFF_XT + j * WDIM + w0;
#pragma unroll
  for (int q = 0; q < 8; ++q)
    *(float4*)(xrow + 4 * q) =
        make_float4(vals[4*q], vals[4*q+1], vals[4*q+2], vals[4*q+3]);
  red1[wg][jj] = s1;
  red2[wg][jj] = s2;
  __syncthreads();
  if (wg == 0) {
    base[OFF_S1 + j] = red1[0][jj] + red1[1][jj] + red1[2][jj] + red1[3][jj];
    base[OFF_S2 + j] = red2[0][jj] + red2[1][jj] + red2[2][jj] + red2[3][jj];
  }
}

// K2: rank (stable desc sort by counting), c_i, scatter esc/esca/perm, u/t.
// grid (8, nb) x 512 : jj = t>>2 covers 128 j's, quarter = t&3 splits compares
__global__ __launch_bounds__(512) void k_rank(float* __restrict__ ws) {
  const int slot = blockIdx.y;
  float* base = ws + (size_t)slot * PBF;
  __shared__ float s2s[KDIM];
  __shared__ float red[512];
  __shared__ int pr[128][4], pc[128][4];
  int t = threadIdx.x;
  for (int i = t; i < KDIM; i += 512) s2s[i] = base[OFF_S2 + i];
  __syncthreads();
  red[t] = fmaxf(s2s[t], s2s[t + 512]);
  __syncthreads();
  for (int s = 256; s > 0; s >>= 1) {
    if (t < s) red[t] = fmaxf(red[t], red[t + s]);
    __syncthreads();
  }
  float M2 = red[0];
  int jj = t >> 2, quarter = t & 3;
  int j = blockIdx.x * 128 + jj;
  float s2me = s2s[j];
  float s1me = base[OFF_S1 + j];
  float key = -s1me;
  int r = 0, c = 0;
  int lo = quarter * 256;
#pragma unroll 4
  for (int k2 = 0; k2 < 256; ++k2) {
    float v = s2s[lo + k2];
    int jp = lo + k2;
    r += (v > s2me || (v == s2me && jp < j)) ? 1 : 0;
    c += (v >= key) ? 1 : 0;
  }
  pr[jj][quarter] = r;
  pc[jj][quarter] = c;
  __syncthreads();
  if (quarter == 0) {
    int R = pr[jj][0] + pr[jj][1] + pr[jj][2] + pr[jj][3];
    int C = pc[jj][0] + pc[jj][1] + pc[jj][2] + pc[jj][3];
    ((int*)(base + OFF_CC))[j] = C;
    ((int*)(base + OFF_PERM))[R] = j;
    base[OFF_ESC + R] = __expf(s2me - M2);
    base[OFF_ESCA + R] = __expf(ALPHA * s2me);
    float z = s1me + M2;
    float mi = z >= 0.f ? z : ALPHA * z;
    base[OFF_U + j] = __expf(z - mi);          // exp(s1+M2-m) <= 1
    base[OFF_T + j] = __expf(ALPHA * s1me - mi);
  }
}

// K3: per-segment vector + scalar totals. grid (NSEG/2, nb) x 256
__global__ __launch_bounds__(256) void k_vtab_tot(float* __restrict__ ws) {
  const int slot = blockIdx.y;
  float* base = ws + (size_t)slot * PBF;
  int t = threadIdx.x;
  int w = t & 127, sl = t >> 7;
  int seg = blockIdx.x * 2 + sl;
  int r0 = seg * SEGLEN;
  const float* xT = base + OFF_XT;
  const int* prm = (const int*)(base + OFF_PERM);
  const float* ea = base + OFF_ESC;
  const float* eb = base + OFF_ESCA;
  float ta = 0.f, tb = 0.f, sa = 0.f, sb = 0.f;
#pragma unroll 4
  for (int k2 = 0; k2 < SEGLEN; ++k2) {
    int r = r0 + k2;
    float eav = ea[r], ebv = eb[r];
    float xv = xT[prm[r] * WDIM + w];
    ta = fmaf(eav, xv, ta);
    tb = fmaf(ebv, xv, tb);
    sa += eav;
    sb += ebv;
  }
  base[OFF_TA + seg * WDIM + w] = ta;
  base[OFF_TB + seg * WDIM + w] = tb;
  if (w == 0) { base[OFF_STA + seg] = sa; base[OFF_STB + seg] = sb; }
}

// K4: fused scan within each segment, bases from totals; writes interleaved
// vector table TAB and scalar table ABT. grid (NSEG/2, nb) x 256
__global__ __launch_bounds__(256) void k_vtab_scan(float* __restrict__ ws) {
  const int slot = blockIdx.y;
  float* base = ws + (size_t)slot * PBF;
  int t = threadIdx.x;
  int w = t & 127, sl = t >> 7;
  int seg = blockIdx.x * 2 + sl;
  int r0 = seg * SEGLEN;
  const float* xT = base + OFF_XT;
  const int* prm = (const int*)(base + OFF_PERM);
  const float* ea = base + OFF_ESC;
  const float* eb = base + OFF_ESCA;
  float baseA = 0.f, baseB = 0.f, basa = 0.f, basb = 0.f;
  for (int s = 0; s < seg; ++s) {
    baseA += base[OFF_TA + s * WDIM + w];
    basa += base[OFF_STA + s];
  }
  for (int s = seg + 1; s < NSEG; ++s) {
    baseB += base[OFF_TB + s * WDIM + w];
    basb += base[OFF_STB + s];
  }
  float* TAB = base + OFF_TAB;
  float acc = baseA, sacc = basa;
#pragma unroll 4
  for (int k2 = 0; k2 < SEGLEN; ++k2) {
    int r = r0 + k2;
    TAB[r * 256 + w] = acc;                      // A(c) = sum of ranks < c
    if (w == 0) base[OFF_ABT + 2 * r] = sacc;
    float eav = ea[r];
    acc = fmaf(eav, xT[prm[r] * WDIM + w], acc);
    sacc += eav;
  }
  if (seg == NSEG - 1) {
    TAB[KDIM * 256 + w] = acc;
    if (w == 0) base[OFF_ABT + 2 * KDIM] = sacc;
  }
  acc = baseB; sacc = basb;
#pragma unroll 4
  for (int k2 = SEGLEN - 1; k2 >= 0; --k2) {
    int r = r0 + k2;
    float ebv = eb[r];
    acc = fmaf(ebv, xT[prm[r] * WDIM + w], acc);
    sacc += ebv;
    TAB[r * 256 + 128 + w] = acc;                // B(c) = sum of ranks >= c
    if (w == 0) base[OFF_ABT + 2 * r + 1] = sacc;
  }
  if (seg == 0) {
    TAB[KDIM * 256 + 128 + w] = 0.f;
    if (w == 0) base[OFF_ABT + 2 * KDIM + 1] = 0.f;
  }
}

// K5: h_i = (u*A(c_i) + t*B(c_i)) / (u*a(c_i) + t*b(c_i)). grid (128, nb) x 256
__global__ __launch_bounds__(256) void k_out(const float* __restrict__ ws,
                                             float* __restrict__ out, int b0) {
  const int slot = blockIdx.y;
  const int b = b0 + slot;
  const float* base = ws + (size_t)slot * PBF;
  int q = blockIdx.x * 256 + threadIdx.x;  // 0..32767
  int i = q >> 5;
  int wq = (q & 31) << 2;
  int c = ((const int*)(base + OFF_CC))[i];
  float u = base[OFF_U + i];
  float tt = base[OFF_T + i];
  float2 ab = *(const float2*)(base + OFF_ABT + 2 * c);
  float rden = 1.f / fmaf(u, ab.x, tt * ab.y);  // den >= 1 (argmax term)
  const float4 A4 = *(const float4*)(base + OFF_TAB + (size_t)c * 256 + wq);
  const float4 B4 = *(const float4*)(base + OFF_TAB + (size_t)c * 256 + 128 + wq);
  float4 o;
  o.x = (u * A4.x + tt * B4.x) * rden;
  o.y = (u * A4.y + tt * B4.y) * rden;
  o.z = (u * A4.z + tt * B4.z) * rden;
  o.w = (u * A4.w + tt * B4.w) * rden;
  *(float4*)(out + (size_t)b * (KDIM * WDIM) + (size_t)q * 4) = o;
}

extern "C" void kernel_launch(void* const* d_in, const int* in_sizes, int n_in,
                              void* d_out, int out_size, void* d_ws, size_t ws_size,
                              hipStream_t stream) {
  const float* x = (const float*)d_in[0];
  const float* w = (const float*)d_in[1];
  float* out = (float*)d_out;
  float* ws = (float*)d_ws;
  const int NB = 32;
  size_t perb = (size_t)PBF * sizeof(float);
  int nbmax = (int)(ws_size / perb);
  if (nbmax < 1) nbmax = 1;
  if (nbmax > NB) nbmax = NB;
  for (int b0 = 0; b0 < NB; b0 += nbmax) {
    int nb = (NB - b0 < nbmax) ? (NB - b0) : nbmax;
    k_s12<<<dim3(16, nb), 256, 0, stream>>>(x, w, ws, b0);
    k_rank<<<dim3(8, nb), 512, 0, stream>>>(ws);
    k_vtab_tot<<<dim3(NSEG / 2, nb), 256, 0, stream>>>(ws);
    k_vtab_scan<<<dim3(NSEG / 2, nb), 256, 0, stream>>>(ws);
    k_out<<<dim3(128, nb), 256, 0, stream>>>(ws, out, b0);
  }
}

// Round 4
// 56.908 us; speedup vs baseline: 1.5302x; 1.5302x over previous
//
#include <hip/hip_runtime.h>

#define ALPHA 0.2f

constexpr int WDIM = 128;
constexpr int KDIM = 1024;
constexpr int NSEG = 64;             // rank segments
constexpr int SEGLEN = KDIM / NSEG;  // 16

// per-batch workspace layout (float offsets)
constexpr int OFF_XT   = 0;        // [1024][128]  v = x^T
constexpr int OFF_TAB  = 131072;   // [1025][256]  A(c) at [c][w], B(c) at [c][128+w]
constexpr int OFF_ESC  = 393472;   // [1024] exp(s2 - M2) sorted desc
constexpr int OFF_ESCA = 394496;   // [1024] exp(alpha*s2) sorted
constexpr int OFF_ABT  = 395520;   // [1025][2] scalar (a(c), b(c))
constexpr int OFF_U    = 397570;   // [1024]
constexpr int OFF_T    = 398594;   // [1024]
constexpr int OFF_S1   = 399618;   // [1024]
constexpr int OFF_S2   = 400642;   // [1024]
constexpr int OFF_CC   = 401666;   // [1024] int: c_i
constexpr int OFF_PERM = 402690;   // [1024] int: perm[rank] = j
constexpr int OFF_TA   = 403840;   // [NSEG][128] segment totals (A)
constexpr int OFF_TB   = 412032;   // [NSEG][128] segment totals (B)
constexpr int OFF_STA  = 420224;   // [NSEG] scalar seg totals (a)
constexpr int OFF_STB  = 420288;   // [NSEG] scalar seg totals (b)
constexpr int OFF_SBA  = 420352;   // [NSEG][128] seg base: sum of segs before
constexpr int OFF_SBB  = 428544;   // [NSEG][128] seg base: sum of segs after
constexpr int PBF      = 436736;   // per-batch stride (floats)

// K1: s1, s2, transpose x -> xT. grid (16, nb) x 256
__global__ __launch_bounds__(256) void k_s12(const float* __restrict__ x,
                                             const float* __restrict__ w,
                                             float* __restrict__ ws, int b0) {
  const int slot = blockIdx.y;
  const int b = b0 + slot;
  float* base = ws + (size_t)slot * PBF;
  __shared__ float w1s[WDIM], w2s[WDIM];
  __shared__ float red1[4][64], red2[4][64];
  int t = threadIdx.x;
  if (t < WDIM) { w1s[t] = w[t]; w2s[t] = w[WDIM + t]; }
  __syncthreads();
  int jj = t & 63, wg = t >> 6;
  int j = blockIdx.x * 64 + jj;
  int w0 = wg * 32;
  const float* xb = x + (size_t)b * (WDIM * KDIM);
  float s1 = 0.f, s2 = 0.f;
  float vals[32];
#pragma unroll
  for (int k = 0; k < 32; ++k) {
    float v = xb[(w0 + k) * KDIM + j];
    vals[k] = v;
    s1 = fmaf(v, w1s[w0 + k], s1);
    s2 = fmaf(v, w2s[w0 + k], s2);
  }
  float* xrow = base + OFF_XT + j * WDIM + w0;
#pragma unroll
  for (int q = 0; q < 8; ++q)
    *(float4*)(xrow + 4 * q) =
        make_float4(vals[4*q], vals[4*q+1], vals[4*q+2], vals[4*q+3]);
  red1[wg][jj] = s1;
  red2[wg][jj] = s2;
  __syncthreads();
  if (wg == 0) {
    base[OFF_S1 + j] = red1[0][jj] + red1[1][jj] + red1[2][jj] + red1[3][jj];
    base[OFF_S2 + j] = red2[0][jj] + red2[1][jj] + red2[2][jj] + red2[3][jj];
  }
}

// K2: rank/count/scatter. grid (8, nb) x 512
__global__ __launch_bounds__(512) void k_rank(float* __restrict__ ws) {
  const int slot = blockIdx.y;
  float* base = ws + (size_t)slot * PBF;
  __shared__ float s2s[KDIM];
  __shared__ float red[512];
  __shared__ int pr[128][4], pc[128][4];
  int t = threadIdx.x;
  for (int i = t; i < KDIM; i += 512) s2s[i] = base[OFF_S2 + i];
  __syncthreads();
  red[t] = fmaxf(s2s[t], s2s[t + 512]);
  __syncthreads();
  for (int s = 256; s > 0; s >>= 1) {
    if (t < s) red[t] = fmaxf(red[t], red[t + s]);
    __syncthreads();
  }
  float M2 = red[0];
  int jj = t >> 2, quarter = t & 3;
  int j = blockIdx.x * 128 + jj;
  float s2me = s2s[j];
  float s1me = base[OFF_S1 + j];
  float key = -s1me;
  int r = 0, c = 0;
  int lo = quarter * 256;
#pragma unroll 4
  for (int k2 = 0; k2 < 256; ++k2) {
    float v = s2s[lo + k2];
    int jp = lo + k2;
    r += (v > s2me || (v == s2me && jp < j)) ? 1 : 0;
    c += (v >= key) ? 1 : 0;
  }
  pr[jj][quarter] = r;
  pc[jj][quarter] = c;
  __syncthreads();
  if (quarter == 0) {
    int R = pr[jj][0] + pr[jj][1] + pr[jj][2] + pr[jj][3];
    int C = pc[jj][0] + pc[jj][1] + pc[jj][2] + pc[jj][3];
    ((int*)(base + OFF_CC))[j] = C;
    ((int*)(base + OFF_PERM))[R] = j;
    base[OFF_ESC + R] = __expf(s2me - M2);
    base[OFF_ESCA + R] = __expf(ALPHA * s2me);
    float z = s1me + M2;
    float mi = z >= 0.f ? z : ALPHA * z;
    base[OFF_U + j] = __expf(z - mi);
    base[OFF_T + j] = __expf(ALPHA * s1me - mi);
  }
}

// K3: per-segment vector + scalar totals. grid (NSEG/2, nb) x 256
__global__ __launch_bounds__(256) void k_tot(float* __restrict__ ws) {
  const int slot = blockIdx.y;
  float* base = ws + (size_t)slot * PBF;
  int t = threadIdx.x;
  int w = t & 127, sl = t >> 7;
  int seg = blockIdx.x * 2 + sl;
  int r0 = seg * SEGLEN;
  const float* xT = base + OFF_XT;
  const int* prm = (const int*)(base + OFF_PERM);
  int pr16[SEGLEN];
#pragma unroll
  for (int k = 0; k < SEGLEN; ++k) pr16[k] = prm[r0 + k];
  float xv[SEGLEN], eav[SEGLEN], ebv[SEGLEN];
#pragma unroll
  for (int k = 0; k < SEGLEN; ++k) {
    xv[k] = xT[pr16[k] * WDIM + w];
    eav[k] = base[OFF_ESC + r0 + k];
    ebv[k] = base[OFF_ESCA + r0 + k];
  }
  float ta = 0.f, tb = 0.f, sa = 0.f, sb = 0.f;
#pragma unroll
  for (int k = 0; k < SEGLEN; ++k) {
    ta = fmaf(eav[k], xv[k], ta);
    tb = fmaf(ebv[k], xv[k], tb);
    sa += eav[k];
    sb += ebv[k];
  }
  base[OFF_TA + seg * WDIM + w] = ta;
  base[OFF_TB + seg * WDIM + w] = tb;
  if (w == 0) { base[OFF_STA + seg] = sa; base[OFF_STB + seg] = sb; }
}

// K4: per-batch base tables (vector, via 2-level scan) + scalar ABT (Hillis).
// grid nb x 1024
__global__ __launch_bounds__(1024) void k_base(float* __restrict__ ws) {
  float* base = ws + (size_t)blockIdx.x * PBF;
  __shared__ float sa[KDIM], sb[KDIM];
  __shared__ float gta[8][128], gtb[8][128];
  int t = threadIdx.x;
  sa[t] = base[OFF_ESC + t];
  sb[t] = base[OFF_ESCA + t];
  __syncthreads();
  for (int s = 1; s < KDIM; s <<= 1) {
    float va = (t >= s) ? sa[t - s] : 0.f;
    float vb = (t + s < KDIM) ? sb[t + s] : 0.f;
    __syncthreads();
    sa[t] += va;
    sb[t] += vb;
    __syncthreads();
  }
  base[OFF_ABT + 2 * (t + 1)] = sa[t];      // a(t+1)
  base[OFF_ABT + 2 * t + 1] = sb[t];        // b(t)
  if (t == 0) { base[OFF_ABT + 0] = 0.f; base[OFF_ABT + 2 * KDIM + 1] = 0.f; }
  // vector bases: 8 groups x 8 segments
  int w = t & 127, g = t >> 7;
  int s0 = g * 8;
  float ta8[8], tb8[8];
  float ga = 0.f, gb = 0.f;
#pragma unroll
  for (int k = 0; k < 8; ++k) {
    ta8[k] = base[OFF_TA + (s0 + k) * WDIM + w];
    tb8[k] = base[OFF_TB + (s0 + k) * WDIM + w];
    ga += ta8[k];
    gb += tb8[k];
  }
  gta[g][w] = ga;
  gtb[g][w] = gb;
  __syncthreads();
  float bA = 0.f, bB = 0.f;
  for (int g2 = 0; g2 < g; ++g2) bA += gta[g2][w];
  for (int g2 = g + 1; g2 < 8; ++g2) bB += gtb[g2][w];
#pragma unroll
  for (int k = 0; k < 8; ++k) {
    base[OFF_SBA + (s0 + k) * WDIM + w] = bA;   // sum of segs before
    bA += ta8[k];
  }
#pragma unroll
  for (int k = 7; k >= 0; --k) {
    base[OFF_SBB + (s0 + k) * WDIM + w] = bB;   // sum of segs after
    bB += tb8[k];
  }
}

// K5: segment scan -> final TAB rows. grid (NSEG, nb) x 128
// All gathers batched into registers (one wait), then pure fmaf+store chains.
__global__ __launch_bounds__(128) void k_scan(float* __restrict__ ws) {
  const int slot = blockIdx.y;
  float* base = ws + (size_t)slot * PBF;
  int seg = blockIdx.x;
  int wl = threadIdx.x;
  int r0 = seg * SEGLEN;
  const float* xT = base + OFF_XT;
  const int* prm = (const int*)(base + OFF_PERM);
  int pr16[SEGLEN];
#pragma unroll
  for (int k = 0; k < SEGLEN; ++k) pr16[k] = prm[r0 + k];
  float xv[SEGLEN], eav[SEGLEN], ebv[SEGLEN];
#pragma unroll
  for (int k = 0; k < SEGLEN; ++k) {
    xv[k] = xT[pr16[k] * WDIM + wl];
    eav[k] = base[OFF_ESC + r0 + k];
    ebv[k] = base[OFF_ESCA + r0 + k];
  }
  float* TAB = base + OFF_TAB;
  float accA = base[OFF_SBA + seg * WDIM + wl];
#pragma unroll
  for (int k = 0; k < SEGLEN; ++k) {
    TAB[(r0 + k) * 256 + wl] = accA;             // A(c) = sum of ranks < c
    accA = fmaf(eav[k], xv[k], accA);
  }
  if (seg == NSEG - 1) TAB[KDIM * 256 + wl] = accA;
  float accB = base[OFF_SBB + seg * WDIM + wl];
#pragma unroll
  for (int k = SEGLEN - 1; k >= 0; --k) {
    accB = fmaf(ebv[k], xv[k], accB);
    TAB[(r0 + k) * 256 + 128 + wl] = accB;       // B(c) = sum of ranks >= c
  }
  if (seg == 0) TAB[KDIM * 256 + 128 + wl] = 0.f;
}

// K6: h_i = (u*A(c_i) + t*B(c_i)) / (u*a(c_i) + t*b(c_i)). grid (128, nb) x 256
__global__ __launch_bounds__(256) void k_out(const float* __restrict__ ws,
                                             float* __restrict__ out, int b0) {
  const int slot = blockIdx.y;
  const int b = b0 + slot;
  const float* base = ws + (size_t)slot * PBF;
  int q = blockIdx.x * 256 + threadIdx.x;  // 0..32767
  int i = q >> 5;
  int wq = (q & 31) << 2;
  int c = ((const int*)(base + OFF_CC))[i];
  float u = base[OFF_U + i];
  float tt = base[OFF_T + i];
  float2 ab = *(const float2*)(base + OFF_ABT + 2 * c);
  float rden = 1.f / fmaf(u, ab.x, tt * ab.y);
  const float4 A4 = *(const float4*)(base + OFF_TAB + (size_t)c * 256 + wq);
  const float4 B4 = *(const float4*)(base + OFF_TAB + (size_t)c * 256 + 128 + wq);
  float4 o;
  o.x = (u * A4.x + tt * B4.x) * rden;
  o.y = (u * A4.y + tt * B4.y) * rden;
  o.z = (u * A4.z + tt * B4.z) * rden;
  o.w = (u * A4.w + tt * B4.w) * rden;
  *(float4*)(out + (size_t)b * (KDIM * WDIM) + (size_t)q * 4) = o;
}

extern "C" void kernel_launch(void* const* d_in, const int* in_sizes, int n_in,
                              void* d_out, int out_size, void* d_ws, size_t ws_size,
                              hipStream_t stream) {
  const float* x = (const float*)d_in[0];
  const float* w = (const float*)d_in[1];
  float* out = (float*)d_out;
  float* ws = (float*)d_ws;
  const int NB = 32;
  size_t perb = (size_t)PBF * sizeof(float);
  int nbmax = (int)(ws_size / perb);
  if (nbmax < 1) nbmax = 1;
  if (nbmax > NB) nbmax = NB;
  for (int b0 = 0; b0 < NB; b0 += nbmax) {
    int nb = (NB - b0 < nbmax) ? (NB - b0) : nbmax;
    k_s12<<<dim3(16, nb), 256, 0, stream>>>(x, w, ws, b0);
    k_rank<<<dim3(8, nb), 512, 0, stream>>>(ws);
    k_tot<<<dim3(NSEG / 2, nb), 256, 0, stream>>>(ws);
    k_base<<<nb, 1024, 0, stream>>>(ws);
    k_scan<<<dim3(NSEG, nb), 128, 0, stream>>>(ws);
    k_out<<<dim3(128, nb), 256, 0, stream>>>(ws, out, b0);
  }
}